// Round 1
// baseline (25656.009 us; speedup 1.0000x reference)
//
#include <hip/hip_runtime.h>
#include <hip/hip_bf16.h>
#include <math.h>

// Problem dims (fixed by reference)
#define NB     64      // batch
#define TT     512     // encoder timesteps
#define KS     256     // key size
#define VS     256     // value size
#define HID    512     // hidden (= KS+VS)
#define GATES  1024    // 4*KS
#define LL     256     // decoder steps
#define VOC    10000
#define SOSTOK 33

__device__ __forceinline__ float sigmoidf_(float x) { return 1.0f / (1.0f + expf(-x)); }

// ---------------------------------------------------------------------------
// Pack kernel: build transposed/concatenated weight matrices + summed biases.
// W1T[k][j] (k<256: W_ih1[j][512+k] = ctx part; k>=256: W_hh1[j][k-256])
// W2T[k][j] (k<256: W_ih2[j][k];               k>=256: W_hh2[j][k-256])
// ---------------------------------------------------------------------------
__global__ __launch_bounds__(256)
void pack_kernel(const float* __restrict__ W_ih1, const float* __restrict__ W_hh1,
                 const float* __restrict__ b_ih1, const float* __restrict__ b_hh1,
                 const float* __restrict__ W_ih2, const float* __restrict__ W_hh2,
                 const float* __restrict__ b_ih2, const float* __restrict__ b_hh2,
                 float* __restrict__ W1T, float* __restrict__ W2T,
                 float* __restrict__ b1s, float* __restrict__ b2s)
{
    int idx = blockIdx.x * 256 + threadIdx.x;
    if (idx < 512 * 1024) {
        int k = idx >> 10;
        int j = idx & 1023;
        W1T[idx] = (k < 256) ? W_ih1[j * 768 + 512 + k] : W_hh1[j * 256 + (k - 256)];
        W2T[idx] = (k < 256) ? W_ih2[j * 256 + k]       : W_hh2[j * 256 + (k - 256)];
    }
    if (idx < 1024) {
        b1s[idx] = b_ih1[idx] + b_hh1[idx];
        b2s[idx] = b_ih2[idx] + b_hh2[idx];
    }
}

// ---------------------------------------------------------------------------
// Generic fp32 NT GEMM: C[m][n] = sum_k A[m*lda+k] * B[n*ldb+k]
// BM=BN=128, BK=16, 256 threads, 8x8 acc per thread.
// MODE 0: plain store to C (row-major, ldc), guards on M and Nn.
// MODE 1: decoder epilogue: m=(t*64+nb) -> out[((nb*LL)+t)*VOC + v] + bias[v]
// ---------------------------------------------------------------------------
template <int MODE>
__global__ __launch_bounds__(256)
void gemm_nt(const float* __restrict__ A, const float* __restrict__ B,
             float* __restrict__ C, const float* __restrict__ bias,
             int M, int Nn, int K, int lda, int ldb, int ldc)
{
    const int BM = 128, BN = 128, BK = 16;
    __shared__ float As[BK][BM + 4];
    __shared__ float Bs[BK][BN + 4];

    const int m0 = blockIdx.y * BM;
    const int n0 = blockIdx.x * BN;
    const int tid = threadIdx.x;
    const int tx = tid & 15;       // 0..15  -> column group
    const int ty = tid >> 4;       // 0..15  -> row group
    const int lr = tid >> 2;       // 0..63  -> load row
    const int lq = tid & 3;        // 0..3   -> load quarter (4 floats)

    float acc[8][8];
#pragma unroll
    for (int i = 0; i < 8; i++)
#pragma unroll
        for (int j = 0; j < 8; j++) acc[i][j] = 0.0f;

    for (int k0 = 0; k0 < K; k0 += BK) {
        // stage A tile (transposed into LDS)
#pragma unroll
        for (int h = 0; h < 2; h++) {
            int r = lr + h * 64;
            int gm = m0 + r;
            float4 v = make_float4(0.f, 0.f, 0.f, 0.f);
            if (gm < M) v = *(const float4*)(A + (size_t)gm * lda + k0 + lq * 4);
            As[lq * 4 + 0][r] = v.x; As[lq * 4 + 1][r] = v.y;
            As[lq * 4 + 2][r] = v.z; As[lq * 4 + 3][r] = v.w;
        }
        // stage B tile
#pragma unroll
        for (int h = 0; h < 2; h++) {
            int r = lr + h * 64;
            int gn = n0 + r;
            float4 v = make_float4(0.f, 0.f, 0.f, 0.f);
            if (gn < Nn) v = *(const float4*)(B + (size_t)gn * ldb + k0 + lq * 4);
            Bs[lq * 4 + 0][r] = v.x; Bs[lq * 4 + 1][r] = v.y;
            Bs[lq * 4 + 2][r] = v.z; Bs[lq * 4 + 3][r] = v.w;
        }
        __syncthreads();

#pragma unroll
        for (int kk = 0; kk < BK; kk++) {
            float a[8], b[8];
            *(float4*)&a[0] = *(const float4*)&As[kk][ty * 4];
            *(float4*)&a[4] = *(const float4*)&As[kk][64 + ty * 4];
            *(float4*)&b[0] = *(const float4*)&Bs[kk][tx * 4];
            *(float4*)&b[4] = *(const float4*)&Bs[kk][64 + tx * 4];
#pragma unroll
            for (int i = 0; i < 8; i++)
#pragma unroll
                for (int j = 0; j < 8; j++) acc[i][j] += a[i] * b[j];
        }
        __syncthreads();
    }

    // epilogue
    int row[8];
#pragma unroll
    for (int i = 0; i < 8; i++) row[i] = m0 + ((i < 4) ? (ty * 4 + i) : (64 + ty * 4 + (i - 4)));
    const int c0 = n0 + tx * 4;
    const int c1 = n0 + 64 + tx * 4;

    if (MODE == 0) {
#pragma unroll
        for (int i = 0; i < 8; i++) {
            if (row[i] >= M) continue;
            float* cp = C + (size_t)row[i] * ldc;
#pragma unroll
            for (int jh = 0; jh < 2; jh++) {
                int cc = jh ? c1 : c0;
                if (cc + 3 < Nn) {
                    *(float4*)(cp + cc) = make_float4(acc[i][jh * 4 + 0], acc[i][jh * 4 + 1],
                                                      acc[i][jh * 4 + 2], acc[i][jh * 4 + 3]);
                } else {
                    for (int j = 0; j < 4; j++)
                        if (cc + j < Nn) cp[cc + j] = acc[i][jh * 4 + j];
                }
            }
        }
    } else {
        float bv0[4], bv1[4];
#pragma unroll
        for (int j = 0; j < 4; j++) {
            bv0[j] = (c0 + j < Nn) ? bias[c0 + j] : 0.f;
            bv1[j] = (c1 + j < Nn) ? bias[c1 + j] : 0.f;
        }
#pragma unroll
        for (int i = 0; i < 8; i++) {
            int m = row[i];           // M=16384 here, always in range
            int t = m >> 6;           // step index
            int nb = m & 63;          // batch index
            float* cp = C + ((size_t)nb * LL + t) * VOC;
#pragma unroll
            for (int jh = 0; jh < 2; jh++) {
                int cc = jh ? c1 : c0;
                float* bv = jh ? bv1 : bv0;
                if (cc + 3 < Nn) {
                    *(float4*)(cp + cc) = make_float4(acc[i][jh * 4 + 0] + bv[0],
                                                      acc[i][jh * 4 + 1] + bv[1],
                                                      acc[i][jh * 4 + 2] + bv[2],
                                                      acc[i][jh * 4 + 3] + bv[3]);
                } else {
                    for (int j = 0; j < 4; j++)
                        if (cc + j < Nn) cp[cc + j] = acc[i][jh * 4 + j] + bv[j];
                }
            }
        }
    }
}

// ---------------------------------------------------------------------------
// Persistent sequential kernel: one block per batch row n, 256 threads.
// Runs all 256 decoder steps; only __syncthreads() (no inter-block deps).
// Stores s_t = [h2 | ctx] into S[t][n][512] for the deferred logits GEMM.
// ---------------------------------------------------------------------------
__global__ __launch_bounds__(256)
void seq_kernel(const float* __restrict__ Vmat,   // values [NB][TT][VS]
                const float* __restrict__ Kmat,   // key    [NB][TT][KS]
                const int* __restrict__ lens,
                const int* __restrict__ text,     // [NB][LL]
                const float* __restrict__ preE,   // [VOC][GATES]  E@W_ih1[:, :512]^T
                const float* __restrict__ W1T,    // [512][GATES]
                const float* __restrict__ W2T,    // [512][GATES]
                const float* __restrict__ b1s,    // [GATES]
                const float* __restrict__ b2s,    // [GATES]
                float* __restrict__ S)            // [LL][NB][HID]
{
    const int n = blockIdx.x;
    const int tid = threadIdx.x;   // 0..255

    __shared__ float h1[KS], c1v[KS], h2[KS], c2v[KS], ctx[VS];
    __shared__ float xv[512];
    __shared__ float attn[TT];
    __shared__ float red[256];

    const int len = lens[n];
    const float* Kn = Kmat + (size_t)n * TT * KS;
    const float* Vn = Vmat + (size_t)n * TT * VS;

    h1[tid] = 0.f; c1v[tid] = 0.f; h2[tid] = 0.f; c2v[tid] = 0.f;
    __syncthreads();

    // ---- attention: energy -> masked softmax -> ctx (all per-n, in-block) ----
    auto attention = [&]() {
        float e0 = -1e10f, e1 = -1e10f;
        {
            int t = tid;
            if (t < len) {
                const float4* kr = (const float4*)(Kn + (size_t)t * KS);
                float acc = 0.f;
#pragma unroll 8
                for (int k4 = 0; k4 < KS / 4; k4++) {
                    float4 kv = kr[k4];
                    acc += kv.x * h2[k4 * 4 + 0];
                    acc += kv.y * h2[k4 * 4 + 1];
                    acc += kv.z * h2[k4 * 4 + 2];
                    acc += kv.w * h2[k4 * 4 + 3];
                }
                e0 = acc;
            }
            t = tid + 256;
            if (t < len) {
                const float4* kr = (const float4*)(Kn + (size_t)t * KS);
                float acc = 0.f;
#pragma unroll 8
                for (int k4 = 0; k4 < KS / 4; k4++) {
                    float4 kv = kr[k4];
                    acc += kv.x * h2[k4 * 4 + 0];
                    acc += kv.y * h2[k4 * 4 + 1];
                    acc += kv.z * h2[k4 * 4 + 2];
                    acc += kv.w * h2[k4 * 4 + 3];
                }
                e1 = acc;
            }
        }
        // block-max
        red[tid] = fmaxf(e0, e1);
        __syncthreads();
#pragma unroll
        for (int s = 128; s > 0; s >>= 1) {
            if (tid < s) red[tid] = fmaxf(red[tid], red[tid + s]);
            __syncthreads();
        }
        float M = red[0];
        __syncthreads();
        float p0 = expf(e0 - M);   // masked -> exp(-1e10-M) == 0 exactly in fp32
        float p1 = expf(e1 - M);
        attn[tid] = p0; attn[tid + 256] = p1;
        red[tid] = p0 + p1;
        __syncthreads();
#pragma unroll
        for (int s = 128; s > 0; s >>= 1) {
            if (tid < s) red[tid] += red[tid + s];
            __syncthreads();
        }
        float inv = 1.0f / red[0];
        // ctx[v] = (sum_t p_t * V[n][t][v]) / sum ; coalesced over v=tid
        float acc = 0.f;
        const float* vb = Vn + tid;
        for (int t = 0; t < len; t++) acc += attn[t] * vb[(size_t)t * VS];
        ctx[tid] = acc * inv;
        __syncthreads();
    };

    // ---- one LSTM cell: gates = [xa|xb] @ WT (+pre) (+bsum) -> update hs,cs ----
    auto lstm = [&](const float* __restrict__ WT, const float* __restrict__ bsum,
                    const float* __restrict__ pre, float* hs, float* cs,
                    const float* xa, const float* xb) {
        xv[tid] = xa[tid];
        xv[256 + tid] = xb[tid];
        __syncthreads();
        float a0 = 0.f, a1 = 0.f, a2 = 0.f, a3 = 0.f;
#pragma unroll 8
        for (int k = 0; k < 512; k++) {
            float x = xv[k];
            const float* wr = WT + (k << 10) + tid;   // coalesced: lane j -> addr j
            a0 += x * wr[0];
            a1 += x * wr[256];
            a2 += x * wr[512];
            a3 += x * wr[768];
        }
        float gi = a0 + bsum[tid];
        float gf = a1 + bsum[tid + 256];
        float gg = a2 + bsum[tid + 512];
        float go = a3 + bsum[tid + 768];
        if (pre) {
            gi += pre[tid];
            gf += pre[tid + 256];
            gg += pre[tid + 512];
            go += pre[tid + 768];
        }
        float c = sigmoidf_(gf) * cs[tid] + sigmoidf_(gi) * tanhf(gg);
        float h = sigmoidf_(go) * tanhf(c);
        __syncthreads();   // all xv/xb reads done before overwriting state
        hs[tid] = h;
        cs[tid] = c;
        __syncthreads();
    };

    attention();   // ctx0 with h2 = 0  (== reference's attend(zeros,...))

    for (int t = 0; t < LL; t++) {
        int tok = (t == 0) ? SOSTOK : text[n * LL + (t - 1)];
        lstm(W1T, b1s, preE + (size_t)tok * GATES, h1, c1v, ctx, h1);
        lstm(W2T, b2s, (const float*)nullptr,      h2, c2v, h1, h2);
        attention();
        float* srow = S + ((size_t)t * NB + n) * HID;
        srow[tid] = h2[tid];
        srow[256 + tid] = ctx[tid];
    }
}

// ---------------------------------------------------------------------------
extern "C" void kernel_launch(void* const* d_in, const int* in_sizes, int n_in,
                              void* d_out, int out_size, void* d_ws, size_t ws_size,
                              hipStream_t stream)
{
    const float* values = (const float*)d_in[0];
    const float* key    = (const float*)d_in[1];
    const int*   lens   = (const int*)d_in[2];
    const int*   text   = (const int*)d_in[3];
    const float* E      = (const float*)d_in[4];
    const float* b_out  = (const float*)d_in[5];
    const float* W_ih1  = (const float*)d_in[6];
    const float* W_hh1  = (const float*)d_in[7];
    const float* b_ih1  = (const float*)d_in[8];
    const float* b_hh1  = (const float*)d_in[9];
    const float* W_ih2  = (const float*)d_in[10];
    const float* W_hh2  = (const float*)d_in[11];
    const float* b_ih2  = (const float*)d_in[12];
    const float* b_hh2  = (const float*)d_in[13];

    float* ws   = (float*)d_ws;
    float* W1T  = ws;                    // 512*1024            = 524288
    float* W2T  = W1T + 524288;          // 512*1024            = 524288
    float* b1s  = W2T + 524288;          // 1024
    float* b2s  = b1s + 1024;            // 1024
    float* preE = b2s + 1024;            // 10000*1024          = 10240000
    float* S    = preE + 10240000;       // 256*64*512          = 8388608
    float* out  = (float*)d_out;         // [64][256][10000]

    // 1) pack transposed weights + bias sums
    hipLaunchKernelGGL(pack_kernel, dim3(2048), dim3(256), 0, stream,
                       W_ih1, W_hh1, b_ih1, b_hh1, W_ih2, W_hh2, b_ih2, b_hh2,
                       W1T, W2T, b1s, b2s);

    // 2) preE[v][j] = sum_{k<512} E[v][k] * W_ih1[j][k]   (embedding part of gates1)
    hipLaunchKernelGGL((gemm_nt<0>), dim3(8, 79), dim3(256), 0, stream,
                       E, W_ih1, preE, (const float*)nullptr,
                       10000, 1024, 512, 512, 768, 1024);

    // 3) sequential decoder: 64 persistent blocks (one per batch row)
    hipLaunchKernelGGL(seq_kernel, dim3(64), dim3(256), 0, stream,
                       values, key, lens, text, preE, W1T, W2T, b1s, b2s, S);

    // 4) logits: out[n][t][v] = S[t][n][:] . E[v][:] + b_out[v]
    hipLaunchKernelGGL((gemm_nt<1>), dim3(79, 128), dim3(256), 0, stream,
                       S, E, out, b_out,
                       16384, 10000, 512, 512, 512, 0);
}